// Round 4
// baseline (158.906 us; speedup 1.0000x reference)
//
#include <hip/hip_runtime.h>

#define HEADS 4
#define NN 256
#define DW 32
#define LOG2E 1.4426950408889634f

typedef __bf16 bf16x8 __attribute__((ext_vector_type(8)));
typedef float f32x4 __attribute__((ext_vector_type(4)));
typedef float f32x16 __attribute__((ext_vector_type(16)));
typedef unsigned int u32x4 __attribute__((ext_vector_type(4)));
typedef unsigned short ushort4v __attribute__((ext_vector_type(4)));

static __device__ __forceinline__ ushort f2bf(float f) {
  __bf16 h = (__bf16)f;
  ushort r;
  __builtin_memcpy(&r, &h, 2);
  return r;
}

static __device__ __forceinline__ unsigned cvt_pk_bf16(float lo, float hi) {
  unsigned r;
  asm("v_cvt_pk_bf16_f32 %0, %1, %2" : "=v"(r) : "v"(lo), "v"(hi));
  return r;
}

// ---------------------------------------------------------------------------
// Triangle bias, transposed + pre-scaled by log2(e):
//   bias_t[h][k][j] = (x[0,j,k,:] . Wb[h] + bb[h]) * LOG2E
// grid = (32 j-tiles of 8, HEADS). thread = k. Each thread accumulates its
// 8 j-values in registers -> two float4 stores (32B contiguous per lane).
// Reads: lane k reads 128B-contiguous x rows (full-line chunks).
// ---------------------------------------------------------------------------
__global__ __launch_bounds__(256) void bias_kernel(
    const float* __restrict__ x, const float* __restrict__ Wb,
    const float* __restrict__ bb, float* __restrict__ bias_t) {
  const int jt = blockIdx.x;
  const int h = blockIdx.y;
  const int k = threadIdx.x;
  float wb[DW];
#pragma unroll
  for (int d = 0; d < DW; ++d) wb[d] = Wb[h * DW + d];  // uniform -> s_loads
  const float bbv = bb[h];
  float b[8];
#pragma unroll
  for (int jj = 0; jj < 8; ++jj) {
    const float* xr = x + ((jt * 8 + jj) * NN + k) * DW;
    float a0 = 0.f, a1 = 0.f;
#pragma unroll
    for (int c = 0; c < 8; ++c) {
      const float4 v = reinterpret_cast<const float4*>(xr)[c];
      a0 += v.x * wb[c * 4 + 0] + v.z * wb[c * 4 + 2];
      a1 += v.y * wb[c * 4 + 1] + v.w * wb[c * 4 + 3];
    }
    b[jj] = (a0 + a1 + bbv) * LOG2E;
  }
  float* dst = bias_t + (h * NN + k) * NN + jt * 8;
  *reinterpret_cast<float4*>(dst) = make_float4(b[0], b[1], b[2], b[3]);
  *reinterpret_cast<float4*>(dst + 4) = make_float4(b[4], b[5], b[6], b[7]);
}

// ---------------------------------------------------------------------------
// Fused QKV projection + attention, swapped-QK 32x32x16 MFMA structure.
// grid = 1024: block = (i = bid>>2, h = bid&3). 4 waves, wave w owns
// queries 64w..64w+63 as two 32-row tiles.
//
// S^T = K·Q^T -> lane l holds q = l&31, 16 keys at (r&3)+8*(r>>2)+4*(l>>5).
// Softmax lane-local, exp2-direct (log2e pre-folded into Q scale and bias).
// P -> PV A-frags in-register via cvt_pk_bf16 + v_permlane32_swap.
// O C-layout cols = d -> coalesced stores.
//
// __launch_bounds__(256,4): VGPR<=128 so 4 blocks/CU -> all 1024 blocks
// resident in ONE round (LDS 38.5KB x4 = 154KB <= 160KB).
// Only ONE barrier total: each wave stages/reads its own 64-row Q band, so
// the Q->K buffer reuse is wave-private; the single barrier precedes the
// main loop (cross-wave K/V/mask visibility). No barriers in the main loop.
// ---------------------------------------------------------------------------
__global__ __launch_bounds__(256, 4) void attn_mfma(
    const float* __restrict__ x, const float* __restrict__ mask,
    const float* __restrict__ Wq, const float* __restrict__ bq,
    const float* __restrict__ Wk, const float* __restrict__ bk,
    const float* __restrict__ Wv, const float* __restrict__ bv,
    const float* __restrict__ bias_t, float* __restrict__ out) {
  __shared__ __align__(16) ushort Kq[NN][40];
  __shared__ __align__(16) ushort Vt[DW][264];
  __shared__ __align__(16) float mk[NN];
  __shared__ __align__(16) float Ls[NN];

  const int bid = blockIdx.x;
  const int i = bid >> 2;
  const int h = bid & 3;
  const int t = threadIdx.x;
  const int w = t >> 6;
  const int l = t & 63;
  const int lo5 = l & 31;
  const int hi = l >> 5;
  const int lr = l & 15;
  const int lq = l >> 4;
  const int rowbase = w * 64;
  const float scale = 0.17677669529663687f * LOG2E;  // log2e/sqrt(32)

  // ---- W B-fragments (16x16x32 layout) for Q,K,V projections ----
  bf16x8 wqf[2], wkf[2], wvf[2];
#pragma unroll
  for (int nt = 0; nt < 2; ++nt) {
    const int dd = nt * 16 + lr;
    const float* rq = Wq + (h * DW + dd) * DW + lq * 8;
    const float* rk = Wk + (h * DW + dd) * DW + lq * 8;
    const float* rv = Wv + (h * DW + dd) * DW + lq * 8;
#pragma unroll
    for (int jj = 0; jj < 8; ++jj) {
      wqf[nt][jj] = (__bf16)rq[jj];
      wkf[nt][jj] = (__bf16)rk[jj];
      wvf[nt][jj] = (__bf16)rv[jj];
    }
  }

  // ---- x A-fragments for this wave's 64 rows (reused for Q,K,V) ----
  bf16x8 af[4];
#pragma unroll
  for (int rt = 0; rt < 4; ++rt) {
    const float* xr = x + (i * NN + rowbase + rt * 16 + lr) * DW + lq * 8;
#pragma unroll
    for (int jj = 0; jj < 8; ++jj) af[rt][jj] = (__bf16)xr[jj];
  }

  // ---- stage Q into Kq (own 64-row band), read own B-frags ----
#pragma unroll
  for (int rt = 0; rt < 4; ++rt) {
#pragma unroll
    for (int nt = 0; nt < 2; ++nt) {
      const int dd = nt * 16 + lr;
      f32x4 z = {0.f, 0.f, 0.f, 0.f};
      f32x4 cq = __builtin_amdgcn_mfma_f32_16x16x32_bf16(af[rt], wqf[nt], z, 0, 0, 0);
      const float bqv = bq[h * DW + dd];
#pragma unroll
      for (int j = 0; j < 4; ++j)
        Kq[rowbase + rt * 16 + lq * 4 + j][dd] = f2bf((cq[j] + bqv) * scale);
    }
  }
  // own-wave write->read: compiler inserts lgkmcnt wait; no barrier needed
  bf16x8 qb[2][2];
#pragma unroll
  for (int qt = 0; qt < 2; ++qt)
#pragma unroll
    for (int dh = 0; dh < 2; ++dh)
      qb[qt][dh] = *(const bf16x8*)&Kq[rowbase + qt * 32 + lo5][dh * 16 + 8 * hi];

  // ---- overwrite own band with K; stage V transposed ----
#pragma unroll
  for (int rt = 0; rt < 4; ++rt) {
#pragma unroll
    for (int nt = 0; nt < 2; ++nt) {
      const int dd = nt * 16 + lr;
      f32x4 z = {0.f, 0.f, 0.f, 0.f};
      f32x4 ck = __builtin_amdgcn_mfma_f32_16x16x32_bf16(af[rt], wkf[nt], z, 0, 0, 0);
      f32x4 cv = __builtin_amdgcn_mfma_f32_16x16x32_bf16(af[rt], wvf[nt], z, 0, 0, 0);
      const float bkv = bk[h * DW + dd];
      const float bvv = bv[h * DW + dd];
#pragma unroll
      for (int j = 0; j < 4; ++j)
        Kq[rowbase + rt * 16 + lq * 4 + j][dd] = f2bf(ck[j] + bkv);
      ushort4v v4;
#pragma unroll
      for (int j = 0; j < 4; ++j) v4[j] = f2bf(cv[j] + bvv);
      *(ushort4v*)&Vt[dd][rowbase + rt * 16 + lq * 4] = v4;
    }
  }
  mk[t] = mask[i * NN + t];
  __syncthreads();  // the single barrier: K/V/mask now visible to all waves

  // ---- main loop over 8 key-blocks of 32; no barriers inside ----
  f32x16 ot[2];
  float lsum[2] = {0.f, 0.f};
#pragma unroll
  for (int qt = 0; qt < 2; ++qt)
#pragma unroll
    for (int r = 0; r < 16; ++r) ot[qt][r] = 0.f;

  const float* bbase = bias_t + (h * NN) * NN;  // [key][q], pre-scaled

#pragma unroll 1
  for (int kb = 0; kb < 8; ++kb) {
    const int kbase = kb * 32;
    // mask values: 4 x float4 broadcast LDS reads (r -> mvv[r>>2][r&3])
    float4 mvv[4];
#pragma unroll
    for (int g = 0; g < 4; ++g)
      mvv[g] = *(const float4*)&mk[kbase + 4 * hi + 8 * g];

    const bf16x8 ka0 = *(const bf16x8*)&Kq[kbase + lo5][8 * hi];
    const bf16x8 ka1 = *(const bf16x8*)&Kq[kbase + lo5][16 + 8 * hi];
    const bf16x8 va0 = *(const bf16x8*)&Vt[lo5][kbase + 8 * hi];
    const bf16x8 va1 = *(const bf16x8*)&Vt[lo5][kbase + 16 + 8 * hi];

#pragma unroll
    for (int qt = 0; qt < 2; ++qt) {
      const int qrow = rowbase + qt * 32 + lo5;
      // bias loads (coalesced along q), issued before the MFMAs consume them
      float bi[16];
      const float* bp = bbase + (kbase + 4 * hi) * NN + qrow;
#pragma unroll
      for (int r = 0; r < 16; ++r)
        bi[r] = bp[((r & 3) + 8 * (r >> 2)) * NN];

      f32x16 st;
      {
        f32x16 z;
#pragma unroll
        for (int r = 0; r < 16; ++r) z[r] = 0.f;
        __builtin_amdgcn_s_setprio(1);
        st = __builtin_amdgcn_mfma_f32_32x32x16_bf16(ka0, qb[qt][0], z, 0, 0, 0);
        st = __builtin_amdgcn_mfma_f32_32x32x16_bf16(ka1, qb[qt][1], st, 0, 0, 0);
        __builtin_amdgcn_s_setprio(0);
      }

      // softmax numerator in place (st <- p), lane-local
      float ls = 0.f;
#pragma unroll
      for (int r = 0; r < 16; ++r) {
        const float p =
            __builtin_amdgcn_exp2f(st[r] + bi[r]) * (&mvv[r >> 2].x)[r & 3];
        st[r] = p;
        ls += p;
      }
      lsum[qt] += ls;

      // P -> A-fragments: cvt_pk pairs + permlane32_swap
#pragma unroll
      for (int half = 0; half < 2; ++half) {
        const int b0 = half * 8;
        unsigned w0, w1, w2, w3;
        {
          unsigned A = cvt_pk_bf16(st[b0 + 0], st[b0 + 1]);
          unsigned B = cvt_pk_bf16(st[b0 + 4], st[b0 + 5]);
          asm volatile("v_permlane32_swap_b32 %0, %1" : "+v"(A), "+v"(B));
          w0 = A; w2 = B;
        }
        {
          unsigned A = cvt_pk_bf16(st[b0 + 2], st[b0 + 3]);
          unsigned B = cvt_pk_bf16(st[b0 + 6], st[b0 + 7]);
          asm volatile("v_permlane32_swap_b32 %0, %1" : "+v"(A), "+v"(B));
          w1 = A; w3 = B;
        }
        u32x4 words = {w0, w1, w2, w3};
        const bf16x8 pf = __builtin_bit_cast(bf16x8, words);
        __builtin_amdgcn_s_setprio(1);
        ot[qt] = __builtin_amdgcn_mfma_f32_32x32x16_bf16(
            pf, half ? va1 : va0, ot[qt], 0, 0, 0);
        __builtin_amdgcn_s_setprio(0);
      }
    }
  }

  // ---- denominators: lane-local + cross-half add, broadcast via LDS ----
#pragma unroll
  for (int qt = 0; qt < 2; ++qt) {
    const float ls = lsum[qt] + __shfl_xor(lsum[qt], 32);
    Ls[rowbase + qt * 32 + lo5] = 1.0f / ls;  // both halves write same value
  }

  // ---- normalize + store (C-layout cols = d -> coalesced 128B segments) ----
#pragma unroll
  for (int qt = 0; qt < 2; ++qt)
#pragma unroll
    for (int r = 0; r < 16; ++r) {
      const int qp = (r & 3) + 8 * (r >> 2) + 4 * hi;
      const int qrow = rowbase + qt * 32 + qp;
      out[((i * NN + qrow) * HEADS + h) * DW + lo5] = ot[qt][r] * Ls[qrow];
    }
}

extern "C" void kernel_launch(void* const* d_in, const int* in_sizes, int n_in,
                              void* d_out, int out_size, void* d_ws,
                              size_t ws_size, hipStream_t stream) {
  const float* x    = (const float*)d_in[0];
  const float* mask = (const float*)d_in[1];
  const float* Wq   = (const float*)d_in[2];
  const float* bq   = (const float*)d_in[3];
  const float* Wk   = (const float*)d_in[4];
  const float* bk   = (const float*)d_in[5];
  const float* Wv   = (const float*)d_in[6];
  const float* bv   = (const float*)d_in[7];
  const float* Wb   = (const float*)d_in[8];
  const float* bb   = (const float*)d_in[9];
  float* out = (float*)d_out;
  float* bias_t = (float*)d_ws;  // HEADS*NN*NN floats = 1 MB

  bias_kernel<<<dim3(32, HEADS), 256, 0, stream>>>(x, Wb, bb, bias_t);
  attn_mfma<<<NN * HEADS, 256, 0, stream>>>(x, mask, Wq, bq, Wk, bk, Wv, bv,
                                            bias_t, out);
}

// Round 5
// 121.530 us; speedup vs baseline: 1.3075x; 1.3075x over previous
//
#include <hip/hip_runtime.h>

#define HEADS 4
#define NN 256
#define DW 32
#define LOG2E 1.4426950408889634f

typedef __bf16 bf16x8 __attribute__((ext_vector_type(8)));
typedef float f32x4 __attribute__((ext_vector_type(4)));
typedef float f32x16 __attribute__((ext_vector_type(16)));
typedef unsigned int u32x4 __attribute__((ext_vector_type(4)));
typedef unsigned short ushort4v __attribute__((ext_vector_type(4)));

static __device__ __forceinline__ ushort f2bf(float f) {
  __bf16 h = (__bf16)f;
  ushort r;
  __builtin_memcpy(&r, &h, 2);
  return r;
}

static __device__ __forceinline__ unsigned cvt_pk_bf16(float lo, float hi) {
  unsigned r;
  asm("v_cvt_pk_bf16_f32 %0, %1, %2" : "=v"(r) : "v"(lo), "v"(hi));
  return r;
}

// ---------------------------------------------------------------------------
// Triangle bias in MFMA-C-operand tiled layout, pre-scaled by log2(e):
//   bias_tl[(((h*8+kb)*2+hi)*256 + q)*16 + r] = (x[q,k,:].Wb[h] + bb[h])*LOG2E
// where k = kb*32 + (r&3) + 8*(r>>2) + 4*hi  (the 32x32x16 C/D layout).
// Each attention lane then reads its 16 tile-bias values as 4 contiguous
// float4s (one 64B line per lane).
// grid = (32 j-tiles of 8, HEADS); thread = k. Thread k owns fixed
// (kb,hi,r); its 8 j-values land at stride 64B; the wave's 64 lanes cover
// complete 64B lines per store instruction.
// ---------------------------------------------------------------------------
__global__ __launch_bounds__(256) void bias_kernel(
    const float* __restrict__ x, const float* __restrict__ Wb,
    const float* __restrict__ bb, float* __restrict__ bias_tl) {
  const int jt = blockIdx.x;
  const int h = blockIdx.y;
  const int k = threadIdx.x;
  const int kb = k >> 5;
  const int c = k & 31;
  const int hi = (c >> 2) & 1;
  const int r = (c & 3) + 4 * (c >> 3);
  float wb[DW];
#pragma unroll
  for (int d = 0; d < DW; ++d) wb[d] = Wb[h * DW + d];  // uniform -> s_loads
  const float bbv = bb[h];
  float* dst = bias_tl + (((h * 8 + kb) * 2 + hi) * NN + jt * 8) * 16 + r;
#pragma unroll
  for (int jj = 0; jj < 8; ++jj) {
    const float* xr = x + ((jt * 8 + jj) * NN + k) * DW;
    float a0 = 0.f, a1 = 0.f;
#pragma unroll
    for (int cc = 0; cc < 8; ++cc) {
      const float4 v = reinterpret_cast<const float4*>(xr)[cc];
      a0 += v.x * wb[cc * 4 + 0] + v.z * wb[cc * 4 + 2];
      a1 += v.y * wb[cc * 4 + 1] + v.w * wb[cc * 4 + 3];
    }
    dst[jj * 16] = (a0 + a1 + bbv) * LOG2E;
  }
}

// ---------------------------------------------------------------------------
// Fused QKV projection + attention, swapped-QK 32x32x16 MFMA structure.
// grid = 1024: block = (i = bid>>2, h = bid&3). 4 waves, wave w owns
// queries 64w..64w+63 as two 32-row tiles.
//
// S^T = K·Q^T -> lane l holds q = l&31, 16 keys at (r&3)+8*(r>>2)+4*(l>>5).
// Bias enters as the MFMA C-operand (tiled layout above). Softmax is
// lane-local, exp2-direct. P -> PV A-frags in-register via cvt_pk_bf16 +
// v_permlane32_swap. O C-layout cols = d -> coalesced stores.
// Bias for the next tile is prefetched (dwordx4 x4) one tile ahead.
//
// __launch_bounds__(256,3): VGPR cap ~170 -> NO spilling (r4 lesson: (256,4)
// forced 64 VGPRs and spilled 100+MB to scratch). 3 blocks/CU.
// ---------------------------------------------------------------------------
__global__ __launch_bounds__(256, 3) void attn_mfma(
    const float* __restrict__ x, const float* __restrict__ mask,
    const float* __restrict__ Wq, const float* __restrict__ bq,
    const float* __restrict__ Wk, const float* __restrict__ bk,
    const float* __restrict__ Wv, const float* __restrict__ bv,
    const float* __restrict__ bias_tl, float* __restrict__ out) {
  __shared__ __align__(16) ushort Kq[NN][40];
  __shared__ __align__(16) ushort Vt[DW][264];
  __shared__ __align__(16) float mk[NN];
  __shared__ __align__(16) float Ls[NN];

  const int bid = blockIdx.x;
  const int i = bid >> 2;
  const int h = bid & 3;
  const int t = threadIdx.x;
  const int w = t >> 6;
  const int l = t & 63;
  const int lo5 = l & 31;
  const int hi = l >> 5;
  const int lr = l & 15;
  const int lq = l >> 4;
  const int rowbase = w * 64;
  const float scale = 0.17677669529663687f * LOG2E;  // log2e/sqrt(32)

  // ---- W B-fragments (16x16x32 layout) for Q,K,V projections ----
  bf16x8 wqf[2], wkf[2], wvf[2];
#pragma unroll
  for (int nt = 0; nt < 2; ++nt) {
    const int dd = nt * 16 + lr;
    const float* rq = Wq + (h * DW + dd) * DW + lq * 8;
    const float* rk = Wk + (h * DW + dd) * DW + lq * 8;
    const float* rv = Wv + (h * DW + dd) * DW + lq * 8;
#pragma unroll
    for (int jj = 0; jj < 8; ++jj) {
      wqf[nt][jj] = (__bf16)rq[jj];
      wkf[nt][jj] = (__bf16)rk[jj];
      wvf[nt][jj] = (__bf16)rv[jj];
    }
  }

  // ---- x A-fragments for this wave's 64 rows (reused for Q,K,V) ----
  bf16x8 af[4];
#pragma unroll
  for (int rt = 0; rt < 4; ++rt) {
    const float* xr = x + (i * NN + rowbase + rt * 16 + lr) * DW + lq * 8;
#pragma unroll
    for (int jj = 0; jj < 8; ++jj) af[rt][jj] = (__bf16)xr[jj];
  }

  // ---- stage Q into Kq (own 64-row band), read own B-frags ----
#pragma unroll
  for (int rt = 0; rt < 4; ++rt) {
#pragma unroll
    for (int nt = 0; nt < 2; ++nt) {
      const int dd = nt * 16 + lr;
      f32x4 z = {0.f, 0.f, 0.f, 0.f};
      f32x4 cq = __builtin_amdgcn_mfma_f32_16x16x32_bf16(af[rt], wqf[nt], z, 0, 0, 0);
      const float bqv = bq[h * DW + dd];
#pragma unroll
      for (int j = 0; j < 4; ++j)
        Kq[rowbase + rt * 16 + lq * 4 + j][dd] = f2bf((cq[j] + bqv) * scale);
    }
  }
  // own-wave write->read: compiler inserts lgkmcnt wait; no barrier needed
  bf16x8 qb[2][2];
#pragma unroll
  for (int qt = 0; qt < 2; ++qt)
#pragma unroll
    for (int dh = 0; dh < 2; ++dh)
      qb[qt][dh] = *(const bf16x8*)&Kq[rowbase + qt * 32 + lo5][dh * 16 + 8 * hi];

  // ---- overwrite own band with K; stage V transposed ----
#pragma unroll
  for (int rt = 0; rt < 4; ++rt) {
#pragma unroll
    for (int nt = 0; nt < 2; ++nt) {
      const int dd = nt * 16 + lr;
      f32x4 z = {0.f, 0.f, 0.f, 0.f};
      f32x4 ck = __builtin_amdgcn_mfma_f32_16x16x32_bf16(af[rt], wkf[nt], z, 0, 0, 0);
      f32x4 cv = __builtin_amdgcn_mfma_f32_16x16x32_bf16(af[rt], wvf[nt], z, 0, 0, 0);
      const float bkv = bk[h * DW + dd];
      const float bvv = bv[h * DW + dd];
#pragma unroll
      for (int j = 0; j < 4; ++j)
        Kq[rowbase + rt * 16 + lq * 4 + j][dd] = f2bf(ck[j] + bkv);
      ushort4v v4;
#pragma unroll
      for (int j = 0; j < 4; ++j) v4[j] = f2bf(cv[j] + bvv);
      *(ushort4v*)&Vt[dd][rowbase + rt * 16 + lq * 4] = v4;
    }
  }
  mk[t] = mask[i * NN + t];
  __syncthreads();  // the single barrier: K/V/mask now visible to all waves

  // ---- main loop over 8 key-blocks of 32; no barriers inside ----
  f32x16 ot[2];
  float lsum[2] = {0.f, 0.f};
#pragma unroll
  for (int qt = 0; qt < 2; ++qt)
#pragma unroll
    for (int r = 0; r < 16; ++r) ot[qt][r] = 0.f;

  // tiled bias base for this (h, hi, wave): lane reads 64B contiguous
  const float* btl = bias_tl + ((h * 8) * 2 + hi) * (NN * 16);

  // prefetch tile (kb=0, qt=0)
  f32x4 bc[4], bn[4];
  {
    const float* p = btl + (rowbase + lo5) * 16;
#pragma unroll
    for (int g = 0; g < 4; ++g) bc[g] = *(const f32x4*)(p + g * 4);
  }

  bf16x8 ka0, ka1, va0, va1;
  float4 mvv[4];

#pragma unroll 1
  for (int kb = 0; kb < 8; ++kb) {
    const int kbase = kb * 32;
    ka0 = *(const bf16x8*)&Kq[kbase + lo5][8 * hi];
    ka1 = *(const bf16x8*)&Kq[kbase + lo5][16 + 8 * hi];
    va0 = *(const bf16x8*)&Vt[lo5][kbase + 8 * hi];
    va1 = *(const bf16x8*)&Vt[lo5][kbase + 16 + 8 * hi];
#pragma unroll
    for (int g = 0; g < 4; ++g)
      mvv[g] = *(const float4*)&mk[kbase + 4 * hi + 8 * g];

    // per-tile body (qt is a literal at each call -> fully static indexing)
    auto tile = [&](const int qt, const f32x4 bcur[4]) {
      f32x16 cc;
#pragma unroll
      for (int g = 0; g < 4; ++g)
#pragma unroll
        for (int e = 0; e < 4; ++e) cc[g * 4 + e] = bcur[g][e];
      __builtin_amdgcn_s_setprio(1);
      f32x16 st = __builtin_amdgcn_mfma_f32_32x32x16_bf16(ka0, qb[qt][0], cc, 0, 0, 0);
      st = __builtin_amdgcn_mfma_f32_32x32x16_bf16(ka1, qb[qt][1], st, 0, 0, 0);
      __builtin_amdgcn_s_setprio(0);

      // softmax numerator in place; pairwise-tree partial sums
#pragma unroll
      for (int r = 0; r < 16; ++r)
        st[r] = __builtin_amdgcn_exp2f(st[r]) * (&mvv[r >> 2].x)[r & 3];
      float s0 = (st[0] + st[1]) + (st[2] + st[3]);
      float s1 = (st[4] + st[5]) + (st[6] + st[7]);
      float s2 = (st[8] + st[9]) + (st[10] + st[11]);
      float s3 = (st[12] + st[13]) + (st[14] + st[15]);
      lsum[qt] += (s0 + s1) + (s2 + s3);

      // P -> A-fragments: cvt_pk pairs + permlane32_swap
#pragma unroll
      for (int half = 0; half < 2; ++half) {
        const int b0 = half * 8;
        unsigned w0, w1, w2, w3;
        {
          unsigned A = cvt_pk_bf16(st[b0 + 0], st[b0 + 1]);
          unsigned B = cvt_pk_bf16(st[b0 + 4], st[b0 + 5]);
          asm volatile("v_permlane32_swap_b32 %0, %1" : "+v"(A), "+v"(B));
          w0 = A; w2 = B;
        }
        {
          unsigned A = cvt_pk_bf16(st[b0 + 2], st[b0 + 3]);
          unsigned B = cvt_pk_bf16(st[b0 + 6], st[b0 + 7]);
          asm volatile("v_permlane32_swap_b32 %0, %1" : "+v"(A), "+v"(B));
          w1 = A; w3 = B;
        }
        u32x4 words = {w0, w1, w2, w3};
        const bf16x8 pf = __builtin_bit_cast(bf16x8, words);
        __builtin_amdgcn_s_setprio(1);
        ot[qt] = __builtin_amdgcn_mfma_f32_32x32x16_bf16(
            pf, half ? va1 : va0, ot[qt], 0, 0, 0);
        __builtin_amdgcn_s_setprio(0);
      }
    };

    // qt = 0: first prefetch (kb, qt=1), then compute
    {
      const float* p = btl + (kb * 2) * (NN * 16) + (rowbase + 32 + lo5) * 16;
#pragma unroll
      for (int g = 0; g < 4; ++g) bn[g] = *(const f32x4*)(p + g * 4);
      tile(0, bc);
#pragma unroll
      for (int g = 0; g < 4; ++g) bc[g] = bn[g];
    }
    // qt = 1: prefetch (kb+1, qt=0) (wrapped; unused on last), then compute
    {
      const int kbn = (kb + 1) & 7;
      const float* p = btl + (kbn * 2) * (NN * 16) + (rowbase + lo5) * 16;
#pragma unroll
      for (int g = 0; g < 4; ++g) bn[g] = *(const f32x4*)(p + g * 4);
      tile(1, bc);
#pragma unroll
      for (int g = 0; g < 4; ++g) bc[g] = bn[g];
    }
  }

  // ---- denominators: lane-local + cross-half add, broadcast via LDS ----
#pragma unroll
  for (int qt = 0; qt < 2; ++qt) {
    const float ls = lsum[qt] + __shfl_xor(lsum[qt], 32);
    Ls[rowbase + qt * 32 + lo5] = 1.0f / ls;  // both halves write same value
  }

  // ---- normalize + store (C-layout cols = d -> coalesced 128B segments) ----
#pragma unroll
  for (int qt = 0; qt < 2; ++qt)
#pragma unroll
    for (int r = 0; r < 16; ++r) {
      const int qp = (r & 3) + 8 * (r >> 2) + 4 * hi;
      const int qrow = rowbase + qt * 32 + qp;
      out[((i * NN + qrow) * HEADS + h) * DW + lo5] = ot[qt][r] * Ls[qrow];
    }
}

extern "C" void kernel_launch(void* const* d_in, const int* in_sizes, int n_in,
                              void* d_out, int out_size, void* d_ws,
                              size_t ws_size, hipStream_t stream) {
  const float* x    = (const float*)d_in[0];
  const float* mask = (const float*)d_in[1];
  const float* Wq   = (const float*)d_in[2];
  const float* bq   = (const float*)d_in[3];
  const float* Wk   = (const float*)d_in[4];
  const float* bk   = (const float*)d_in[5];
  const float* Wv   = (const float*)d_in[6];
  const float* bv   = (const float*)d_in[7];
  const float* Wb   = (const float*)d_in[8];
  const float* bb   = (const float*)d_in[9];
  float* out = (float*)d_out;
  float* bias_tl = (float*)d_ws;  // HEADS*8*2*256*16 floats = 1 MB

  bias_kernel<<<dim3(32, HEADS), 256, 0, stream>>>(x, Wb, bb, bias_tl);
  attn_mfma<<<NN * HEADS, 256, 0, stream>>>(x, mask, Wq, bq, Wk, bk, Wv, bv,
                                            bias_tl, out);
}

// Round 6
// 113.470 us; speedup vs baseline: 1.4004x; 1.0710x over previous
//
#include <hip/hip_runtime.h>

#define HEADS 4
#define NN 256
#define DW 32
#define LOG2E 1.4426950408889634f

typedef __bf16 bf16x8 __attribute__((ext_vector_type(8)));
typedef float f32x4 __attribute__((ext_vector_type(4)));
typedef float f32x16 __attribute__((ext_vector_type(16)));
typedef unsigned int u32x4 __attribute__((ext_vector_type(4)));
typedef unsigned short ushort4v __attribute__((ext_vector_type(4)));

static __device__ __forceinline__ ushort f2bf(float f) {
  __bf16 h = (__bf16)f;
  ushort r;
  __builtin_memcpy(&r, &h, 2);
  return r;
}

static __device__ __forceinline__ unsigned cvt_pk_bf16(float lo, float hi) {
  unsigned r;
  asm("v_cvt_pk_bf16_f32 %0, %1, %2" : "=v"(r) : "v"(lo), "v"(hi));
  return r;
}

// ---------------------------------------------------------------------------
// Triangle bias in wave-coalesced MFMA-C tile layout, pre-scaled by log2(e):
//   bias2[((((h*8+kb)*4+g)*2+hi)*256 + q)*4 + e] = (x[q,k,:].Wb[h]+bb[h])*LOG2E
// with k = kb*32 + 8*g + 4*hi + e  (matches the 32x32x16 C/D row index
// r = 4g+e used by the attention kernel: key = (r&3)+8*(r>>2)+4*hi).
// One block per q-row. x[q,:,:] (32KB) is staged to LDS with fully
// per-instruction-coalesced dwordx4 loads (the r5 kernel's lane-per-row
// global reads cost ~64 TA cycles/instr -> ~20us; this removes that).
// Thread t then owns key k=t: 8 LDS b128 reads (pad-36, 8-way conflict on
// 8 instrs only) + 128 FMA + 4 scattered dword writes (1MB total, harmless).
// ---------------------------------------------------------------------------
__global__ __launch_bounds__(256) void bias_kernel(
    const float* __restrict__ x, const float* __restrict__ Wb,
    const float* __restrict__ bb, float* __restrict__ bias2) {
  __shared__ float xs[NN * 36];  // [k][36] pad-36: b128-aligned rows

  const int q = blockIdx.x;
  const int t = threadIdx.x;

  // coalesced stage: 8 x dwordx4 per thread, contiguous per instruction
  const float* xr = x + q * (NN * DW);
#pragma unroll
  for (int cc = 0; cc < 8; ++cc) {
    const int f = (cc * 256 + t) * 4;  // flat dword index
    const float4 v = *reinterpret_cast<const float4*>(xr + f);
    const int k = f >> 5;
    const int d = f & 31;
    *reinterpret_cast<float4*>(&xs[k * 36 + d]) = v;
  }
  __syncthreads();

  // thread t = key k: read own row from LDS
  float xv[DW];
#pragma unroll
  for (int c = 0; c < 8; ++c) {
    const float4 v = *reinterpret_cast<const float4*>(&xs[t * 36 + c * 4]);
    xv[c * 4 + 0] = v.x; xv[c * 4 + 1] = v.y;
    xv[c * 4 + 2] = v.z; xv[c * 4 + 3] = v.w;
  }

  const int kb = t >> 5;
  const int c2 = t & 31;
  const int e = c2 & 3;
  const int hi = (c2 >> 2) & 1;
  const int g = c2 >> 3;

#pragma unroll
  for (int h = 0; h < HEADS; ++h) {
    float a0 = 0.f, a1 = 0.f;
#pragma unroll
    for (int d = 0; d < DW; d += 2) {
      a0 += xv[d] * Wb[h * DW + d];        // Wb uniform -> s_loads
      a1 += xv[d + 1] * Wb[h * DW + d + 1];
    }
    bias2[((((h * 8 + kb) * 4 + g) * 2 + hi) * NN + q) * 4 + e] =
        (a0 + a1 + bb[h]) * LOG2E;
  }
}

// ---------------------------------------------------------------------------
// Fused QKV projection + attention, swapped-QK 32x32x16 MFMA structure.
// grid = 1024: block = (i = bid>>2, h = bid&3). 4 waves, wave w owns
// queries 64w..64w+63 as two 32-row tiles.
//
// S^T = K·Q^T -> lane l holds q = l&31, 16 keys at (r&3)+8*(r>>2)+4*(l>>5).
// Bias enters as the MFMA C-operand via the bias2 layout above: load g is
// two fully-used 512B segments per instruction (was 4x sector-amplified).
// Softmax lane-local, exp2-direct. P -> PV A-frags in-register via
// cvt_pk_bf16 + v_permlane32_swap. O C-layout cols = d -> coalesced stores.
// Bias for the next tile is prefetched one tile ahead (double-buffered).
//
// __launch_bounds__(256,3): VGPR cap ~170 -> NO spilling (r4 lesson: (256,4)
// allocated 64 VGPRs and spilled 100+MB to scratch). 3 blocks/CU.
// ---------------------------------------------------------------------------
__global__ __launch_bounds__(256, 3) void attn_mfma(
    const float* __restrict__ x, const float* __restrict__ mask,
    const float* __restrict__ Wq, const float* __restrict__ bq,
    const float* __restrict__ Wk, const float* __restrict__ bk,
    const float* __restrict__ Wv, const float* __restrict__ bv,
    const float* __restrict__ bias2, float* __restrict__ out) {
  __shared__ __align__(16) ushort Kq[NN][40];
  __shared__ __align__(16) ushort Vt[DW][264];
  __shared__ __align__(16) float mk[NN];
  __shared__ __align__(16) float Ls[NN];

  const int bid = blockIdx.x;
  const int i = bid >> 2;
  const int h = bid & 3;
  const int t = threadIdx.x;
  const int w = t >> 6;
  const int l = t & 63;
  const int lo5 = l & 31;
  const int hi = l >> 5;
  const int lr = l & 15;
  const int lq = l >> 4;
  const int rowbase = w * 64;
  const float scale = 0.17677669529663687f * LOG2E;  // log2e/sqrt(32)

  // ---- W B-fragments (16x16x32 layout) for Q,K,V projections ----
  bf16x8 wqf[2], wkf[2], wvf[2];
#pragma unroll
  for (int nt = 0; nt < 2; ++nt) {
    const int dd = nt * 16 + lr;
    const float* rq = Wq + (h * DW + dd) * DW + lq * 8;
    const float* rk = Wk + (h * DW + dd) * DW + lq * 8;
    const float* rv = Wv + (h * DW + dd) * DW + lq * 8;
#pragma unroll
    for (int jj = 0; jj < 8; ++jj) {
      wqf[nt][jj] = (__bf16)rq[jj];
      wkf[nt][jj] = (__bf16)rk[jj];
      wvf[nt][jj] = (__bf16)rv[jj];
    }
  }

  // ---- x A-fragments for this wave's 64 rows (reused for Q,K,V) ----
  bf16x8 af[4];
#pragma unroll
  for (int rt = 0; rt < 4; ++rt) {
    const float* xr = x + (i * NN + rowbase + rt * 16 + lr) * DW + lq * 8;
#pragma unroll
    for (int jj = 0; jj < 8; ++jj) af[rt][jj] = (__bf16)xr[jj];
  }

  // ---- stage Q into Kq (own 64-row band), read own B-frags ----
#pragma unroll
  for (int rt = 0; rt < 4; ++rt) {
#pragma unroll
    for (int nt = 0; nt < 2; ++nt) {
      const int dd = nt * 16 + lr;
      f32x4 z = {0.f, 0.f, 0.f, 0.f};
      f32x4 cq = __builtin_amdgcn_mfma_f32_16x16x32_bf16(af[rt], wqf[nt], z, 0, 0, 0);
      const float bqv = bq[h * DW + dd];
#pragma unroll
      for (int j = 0; j < 4; ++j)
        Kq[rowbase + rt * 16 + lq * 4 + j][dd] = f2bf((cq[j] + bqv) * scale);
    }
  }
  // own-wave write->read: compiler inserts lgkmcnt wait; no barrier needed
  bf16x8 qb[2][2];
#pragma unroll
  for (int qt = 0; qt < 2; ++qt)
#pragma unroll
    for (int dh = 0; dh < 2; ++dh)
      qb[qt][dh] = *(const bf16x8*)&Kq[rowbase + qt * 32 + lo5][dh * 16 + 8 * hi];

  // ---- overwrite own band with K; stage V transposed ----
#pragma unroll
  for (int rt = 0; rt < 4; ++rt) {
#pragma unroll
    for (int nt = 0; nt < 2; ++nt) {
      const int dd = nt * 16 + lr;
      f32x4 z = {0.f, 0.f, 0.f, 0.f};
      f32x4 ck = __builtin_amdgcn_mfma_f32_16x16x32_bf16(af[rt], wkf[nt], z, 0, 0, 0);
      f32x4 cv = __builtin_amdgcn_mfma_f32_16x16x32_bf16(af[rt], wvf[nt], z, 0, 0, 0);
      const float bkv = bk[h * DW + dd];
      const float bvv = bv[h * DW + dd];
#pragma unroll
      for (int j = 0; j < 4; ++j)
        Kq[rowbase + rt * 16 + lq * 4 + j][dd] = f2bf(ck[j] + bkv);
      ushort4v v4;
#pragma unroll
      for (int j = 0; j < 4; ++j) v4[j] = f2bf(cv[j] + bvv);
      *(ushort4v*)&Vt[dd][rowbase + rt * 16 + lq * 4] = v4;
    }
  }
  mk[t] = mask[i * NN + t];
  __syncthreads();  // the single barrier: K/V/mask now visible to all waves

  // ---- main loop over 8 key-blocks of 32; no barriers inside ----
  f32x16 ot[2];
  float lsum[2] = {0.f, 0.f};
#pragma unroll
  for (int qt = 0; qt < 2; ++qt)
#pragma unroll
    for (int r = 0; r < 16; ++r) ot[qt][r] = 0.f;

  // bias2 per-head base; per tile: load g at stride 2048 dwords (8KB),
  // each instruction = two fully-used 512B segments (hi 0/1 halves).
  const float* btl = bias2 + h * (8 * 4 * 2 * NN * 4) + hi * (NN * 4);

  // prefetch tile (kb=0, qt=0)
  f32x4 bc[4], bn[4];
  {
    const float* p = btl + (rowbase + lo5) * 4;
#pragma unroll
    for (int g = 0; g < 4; ++g) bc[g] = *(const f32x4*)(p + g * (2 * NN * 4));
  }

  bf16x8 ka0, ka1, va0, va1;
  float4 mvv[4];

#pragma unroll 1
  for (int kb = 0; kb < 8; ++kb) {
    const int kbase = kb * 32;
    ka0 = *(const bf16x8*)&Kq[kbase + lo5][8 * hi];
    ka1 = *(const bf16x8*)&Kq[kbase + lo5][16 + 8 * hi];
    va0 = *(const bf16x8*)&Vt[lo5][kbase + 8 * hi];
    va1 = *(const bf16x8*)&Vt[lo5][kbase + 16 + 8 * hi];
#pragma unroll
    for (int g = 0; g < 4; ++g)
      mvv[g] = *(const float4*)&mk[kbase + 4 * hi + 8 * g];

    // per-tile body (qt is a literal at each call -> fully static indexing)
    auto tile = [&](const int qt, const f32x4 bcur[4]) {
      f32x16 cc;
#pragma unroll
      for (int g = 0; g < 4; ++g)
#pragma unroll
        for (int e = 0; e < 4; ++e) cc[g * 4 + e] = bcur[g][e];
      __builtin_amdgcn_s_setprio(1);
      f32x16 st = __builtin_amdgcn_mfma_f32_32x32x16_bf16(ka0, qb[qt][0], cc, 0, 0, 0);
      st = __builtin_amdgcn_mfma_f32_32x32x16_bf16(ka1, qb[qt][1], st, 0, 0, 0);
      __builtin_amdgcn_s_setprio(0);

      // softmax numerator in place; pairwise-tree partial sums
#pragma unroll
      for (int r = 0; r < 16; ++r)
        st[r] = __builtin_amdgcn_exp2f(st[r]) * (&mvv[r >> 2].x)[r & 3];
      float s0 = (st[0] + st[1]) + (st[2] + st[3]);
      float s1 = (st[4] + st[5]) + (st[6] + st[7]);
      float s2 = (st[8] + st[9]) + (st[10] + st[11]);
      float s3 = (st[12] + st[13]) + (st[14] + st[15]);
      lsum[qt] += (s0 + s1) + (s2 + s3);

      // P -> A-fragments: cvt_pk pairs + permlane32_swap
#pragma unroll
      for (int half = 0; half < 2; ++half) {
        const int b0 = half * 8;
        unsigned w0, w1, w2, w3;
        {
          unsigned A = cvt_pk_bf16(st[b0 + 0], st[b0 + 1]);
          unsigned B = cvt_pk_bf16(st[b0 + 4], st[b0 + 5]);
          asm volatile("v_permlane32_swap_b32 %0, %1" : "+v"(A), "+v"(B));
          w0 = A; w2 = B;
        }
        {
          unsigned A = cvt_pk_bf16(st[b0 + 2], st[b0 + 3]);
          unsigned B = cvt_pk_bf16(st[b0 + 6], st[b0 + 7]);
          asm volatile("v_permlane32_swap_b32 %0, %1" : "+v"(A), "+v"(B));
          w1 = A; w3 = B;
        }
        u32x4 words = {w0, w1, w2, w3};
        const bf16x8 pf = __builtin_bit_cast(bf16x8, words);
        __builtin_amdgcn_s_setprio(1);
        ot[qt] = __builtin_amdgcn_mfma_f32_32x32x16_bf16(
            pf, half ? va1 : va0, ot[qt], 0, 0, 0);
        __builtin_amdgcn_s_setprio(0);
      }
    };

    // qt = 0: first prefetch (kb, qt=1), then compute
    {
      const float* p = btl + kb * (8 * NN * 4) + (rowbase + 32 + lo5) * 4;
#pragma unroll
      for (int g = 0; g < 4; ++g) bn[g] = *(const f32x4*)(p + g * (2 * NN * 4));
      tile(0, bc);
#pragma unroll
      for (int g = 0; g < 4; ++g) bc[g] = bn[g];
    }
    // qt = 1: prefetch (kb+1, qt=0) (wrapped; unused on last), then compute
    {
      const int kbn = (kb + 1) & 7;
      const float* p = btl + kbn * (8 * NN * 4) + (rowbase + lo5) * 4;
#pragma unroll
      for (int g = 0; g < 4; ++g) bn[g] = *(const f32x4*)(p + g * (2 * NN * 4));
      tile(1, bc);
#pragma unroll
      for (int g = 0; g < 4; ++g) bc[g] = bn[g];
    }
  }

  // ---- denominators: lane-local + cross-half add, broadcast via LDS ----
#pragma unroll
  for (int qt = 0; qt < 2; ++qt) {
    const float ls = lsum[qt] + __shfl_xor(lsum[qt], 32);
    Ls[rowbase + qt * 32 + lo5] = 1.0f / ls;  // both halves write same value
  }

  // ---- normalize + store (C-layout cols = d -> coalesced 128B segments) ----
#pragma unroll
  for (int qt = 0; qt < 2; ++qt)
#pragma unroll
    for (int r = 0; r < 16; ++r) {
      const int qp = (r & 3) + 8 * (r >> 2) + 4 * hi;
      const int qrow = rowbase + qt * 32 + qp;
      out[((i * NN + qrow) * HEADS + h) * DW + lo5] = ot[qt][r] * Ls[qrow];
    }
}

extern "C" void kernel_launch(void* const* d_in, const int* in_sizes, int n_in,
                              void* d_out, int out_size, void* d_ws,
                              size_t ws_size, hipStream_t stream) {
  const float* x    = (const float*)d_in[0];
  const float* mask = (const float*)d_in[1];
  const float* Wq   = (const float*)d_in[2];
  const float* bq   = (const float*)d_in[3];
  const float* Wk   = (const float*)d_in[4];
  const float* bk   = (const float*)d_in[5];
  const float* Wv   = (const float*)d_in[6];
  const float* bv   = (const float*)d_in[7];
  const float* Wb   = (const float*)d_in[8];
  const float* bb   = (const float*)d_in[9];
  float* out = (float*)d_out;
  float* bias2 = (float*)d_ws;  // HEADS*8*4*2*256*4 floats = 1 MB

  bias_kernel<<<NN, 256, 0, stream>>>(x, Wb, bb, bias2);
  attn_mfma<<<NN * HEADS, 256, 0, stream>>>(x, mask, Wq, bq, Wk, bk, Wv, bv,
                                            bias2, out);
}